// Round 7
// baseline (205.415 us; speedup 1.0000x reference)
//
#include <hip/hip_runtime.h>
#include <stdint.h>

// GRU: B=4096, T=128, I=16, H=64. Gate order r,z,n (PyTorch).
// v6: DUAL-CHAIN waves. RB=32 per block (two full 16-batch groups), 128
// blocks, 4 waves. Each wave owns hidden [16wv,16wv+16) for BOTH groups:
// 2 independent recurrence chains interleaved in one instruction stream
// (42 MFMAs + 8 gate cells/lane/step). v2-v5 showed step time ~2000cyc is
// chain-latency-bound (work-invariant); v4 showed independent chains overlap
// at ~80% efficiency. Full tiles + shared W-frags avoid v4's 2x MFMA cost.
// ROWB 272->288 fixes v5's 15.7M bank conflicts (72=8 mod 32 -> bank=12b,
// uniform 2-way). Swapped-operand GEMM (W@h), split-bf16 3-term recurrence,
// exp2 scales pre-folded, biases in MFMA C-init. 1 barrier/step.

#define T_STEPS 128
#define NI 16
#define NH 64
#define RB 32
#define ROWB 288   // bytes per batch col: 128 hi + 128 lo + 32 pad (18x16B)

typedef float    f32x4  __attribute__((ext_vector_type(4)));
typedef uint32_t u32x4  __attribute__((ext_vector_type(4)));
typedef uint32_t u32x2  __attribute__((ext_vector_type(2)));
typedef short    bf16x8 __attribute__((ext_vector_type(8)));  // MFMA operand
typedef __bf16   bfv8   __attribute__((ext_vector_type(8)));

static constexpr float LOG2E = 1.4426950408889634f;

static __device__ __forceinline__ uint32_t fbits(float f) { return __builtin_bit_cast(uint32_t, f); }
static __device__ __forceinline__ float    bitsf(uint32_t u) { return __builtin_bit_cast(float, u); }

static __device__ __forceinline__ bf16x8 ld_frag16(const unsigned char* p) {
  u32x4 v = *(const u32x4*)p;                           // ds_read_b128
  return __builtin_bit_cast(bf16x8, v);
}

#define MFMA(A, B, C) __builtin_amdgcn_mfma_f32_16x16x32_bf16(A, B, C, 0, 0, 0)

// pack split-bf16 x fragment (proven v5 pattern)
static __device__ __forceinline__ bf16x8 pack_xfrag(f32x4 xa, f32x4 xb, bool hi_grp) {
  float v[8];
  #pragma unroll
  for (int j = 0; j < 4; ++j) {
    float x0 = xa[j], x1 = xb[j];
    float b0 = bitsf(fbits(x0) & 0xffff0000u);
    float b1 = bitsf(fbits(x1) & 0xffff0000u);
    v[j]     = hi_grp ? x0 : (x0 - b0);
    v[4 + j] = hi_grp ? x1 : (x1 - b1);
  }
  uint32_t d0 = __builtin_amdgcn_perm(fbits(v[1]), fbits(v[0]), 0x07060302u);
  uint32_t d1 = __builtin_amdgcn_perm(fbits(v[3]), fbits(v[2]), 0x07060302u);
  uint32_t d2 = __builtin_amdgcn_perm(fbits(v[5]), fbits(v[4]), 0x07060302u);
  uint32_t d3 = __builtin_amdgcn_perm(fbits(v[7]), fbits(v[6]), 0x07060302u);
  u32x4 u = {d0, d1, d2, d3};
  return __builtin_bit_cast(bf16x8, u);
}

// 4 gate cells + h update + packed hi/lo LDS write (proven v5 math)
static __device__ __forceinline__ void gates4(const f32x4& aR, const f32x4& aZ,
                                              const f32x4& aNh, const f32x4& aNx,
                                              float* hreg, unsigned char* base,
                                              int wr_hi, int wr_lo) {
  float h[4];
  #pragma unroll
  for (int q = 0; q < 4; ++q) {
    float r = __builtin_amdgcn_rcpf(1.0f + __builtin_amdgcn_exp2f(aR[q]));
    float z = __builtin_amdgcn_rcpf(1.0f + __builtin_amdgcn_exp2f(aZ[q]));
    float n = fmaf(-2.0f, __builtin_amdgcn_rcpf(
                  __builtin_amdgcn_exp2f(fmaf(r, aNh[q], aNx[q])) + 1.0f), 1.0f);
    h[q] = n + z * (hreg[q] - n);
    hreg[q] = h[q];
  }
  uint32_t hi01 = __builtin_amdgcn_perm(fbits(h[1]), fbits(h[0]), 0x07060302u);
  uint32_t hi23 = __builtin_amdgcn_perm(fbits(h[3]), fbits(h[2]), 0x07060302u);
  float l0 = h[0] - bitsf(fbits(h[0]) & 0xffff0000u);
  float l1 = h[1] - bitsf(fbits(h[1]) & 0xffff0000u);
  float l2 = h[2] - bitsf(fbits(h[2]) & 0xffff0000u);
  float l3 = h[3] - bitsf(fbits(h[3]) & 0xffff0000u);
  uint32_t lo01 = __builtin_amdgcn_perm(fbits(l1), fbits(l0), 0x07060302u);
  uint32_t lo23 = __builtin_amdgcn_perm(fbits(l3), fbits(l2), 0x07060302u);
  u32x2 whiv = {hi01, hi23};
  u32x2 wlov = {lo01, lo23};
  *(u32x2*)(base + wr_hi) = whiv;
  *(u32x2*)(base + wr_lo) = wlov;
}

__global__ __launch_bounds__(256, 1)
void gru_fused(const float* __restrict__ x,
               const float* __restrict__ w_ih,
               const float* __restrict__ w_hh,
               const float* __restrict__ b_ih,
               const float* __restrict__ b_hh,
               const float* __restrict__ fc_w,
               const float* __restrict__ fc_b,
               float* __restrict__ out)
{
  __shared__ __align__(16) unsigned char sH[2][16 * ROWB];  // per-group h
  __shared__ float s_red[2][4][16];

  const int tid  = threadIdx.x;
  const int lane = tid & 63;
  const int wv   = tid >> 6;       // wave 0..3: hidden [16wv,16wv+16)
  const int colg = lane & 15;      // batch column within group
  const int grp  = lane >> 4;      // k-group / C row-group
  const int rb   = blockIdx.x * RB;
  const int hc   = wv * 16 + colg;

  // zero both h buffers (h0 = 0): 2*4608 B = 2304 dwords
  for (int i = tid; i < 2304; i += 256) ((uint32_t*)sH)[i] = 0u;

  // ---- W A-frags (shared by both groups), scales pre-folded ----
  const float scl0 = -LOG2E, scl2 = 2.0f * LOG2E;
  bf16x8 whi[3][2], wlo[3][2], axw[3];
  #pragma unroll
  for (int g = 0; g < 3; ++g) {
    const float s = (g == 2) ? scl2 : scl0;
    const float* wr = w_hh + (size_t)(g * 64 + hc) * NH + grp * 8;
    #pragma unroll
    for (int kt = 0; kt < 2; ++kt) {
      bfv8 vhi, vlo;
      #pragma unroll
      for (int j = 0; j < 8; ++j) {
        float w = wr[kt * 32 + j] * s;
        __bf16 hi = (__bf16)w;                 // RNE
        vhi[j] = hi;
        vlo[j] = (__bf16)(w - (float)hi);
      }
      whi[g][kt] = __builtin_bit_cast(bf16x8, vhi);
      wlo[g][kt] = __builtin_bit_cast(bf16x8, vlo);
    }
    const float* wi = w_ih + (size_t)(g * 64 + hc) * NI + (grp & 1) * 8;
    bfv8 vx;
    #pragma unroll
    for (int j = 0; j < 8; ++j) vx[j] = (__bf16)(wi[j] * s);
    axw[g] = __builtin_bit_cast(bf16x8, vx);
  }

  // per-reg biases (C-init); reg q -> hidden wv*16 + grp*4 + q (shared)
  f32x4 bR4, bZ4, bNh4, bNx4;
  #pragma unroll
  for (int q = 0; q < 4; ++q) {
    const int hx = wv * 16 + grp * 4 + q;
    bR4[q]  = scl0 * (b_ih[hx] + b_hh[hx]);
    bZ4[q]  = scl0 * (b_ih[64 + hx] + b_hh[64 + hx]);
    bNh4[q] = scl2 * b_hh[128 + hx];
    bNx4[q] = scl2 * b_ih[128 + hx];
  }

  // ---- LDS addressing (t-invariant), 16B-chunk XOR swizzle ----
  const int swz = colg & 7;
  const int rd_hi0 = colg * ROWB + ((0 * 4 + grp) ^ swz) * 16;
  const int rd_hi1 = colg * ROWB + ((1 * 4 + grp) ^ swz) * 16;
  const int rd_lo0 = rd_hi0 + 128;
  const int rd_lo1 = rd_hi1 + 128;
  const int wch    = (2 * wv + (grp >> 1)) ^ swz;
  const int wr_hi  = colg * ROWB + wch * 16 + (grp & 1) * 8;
  const int wr_lo  = wr_hi + 128;

  float hregA[4] = {0.f, 0.f, 0.f, 0.f};
  float hregB[4] = {0.f, 0.f, 0.f, 0.f};

  // per-lane x pointers (group A: rows rb..rb+15, B: rb+16..rb+31)
  const float* xpA = x + (size_t)(rb + colg) * T_STEPS * NI + (grp & 1) * 8;
  const float* xpB = xpA + (size_t)16 * T_STEPS * NI;
  const bool hi_grp = (grp < 2);

  // t=0 fragments pre-packed
  bf16x8 xfA = pack_xfrag(*(const f32x4*)xpA, *(const f32x4*)(xpA + 4), hi_grp);
  bf16x8 xfB = pack_xfrag(*(const f32x4*)xpB, *(const f32x4*)(xpB + 4), hi_grp);

  __syncthreads();

  for (int t = 0; t < T_STEPS; ++t) {
    // issue next step's x loads first (max cover before use)
    const int tn = (t < T_STEPS - 1) ? (t + 1) : t;
    f32x4 xnaA = *(const f32x4*)(xpA + (size_t)tn * NI);
    f32x4 xnbA = *(const f32x4*)(xpA + (size_t)tn * NI + 4);
    f32x4 xnaB = *(const f32x4*)(xpB + (size_t)tn * NI);
    f32x4 xnbB = *(const f32x4*)(xpB + (size_t)tn * NI + 4);

    // h B-frags, both groups
    const unsigned char* bA = sH[0];
    const unsigned char* bB = sH[1];
    bf16x8 Ahi0 = ld_frag16(bA + rd_hi0), Ahi1 = ld_frag16(bA + rd_hi1);
    bf16x8 Alo0 = ld_frag16(bA + rd_lo0), Alo1 = ld_frag16(bA + rd_lo1);
    bf16x8 Bhi0 = ld_frag16(bB + rd_hi0), Bhi1 = ld_frag16(bB + rd_hi1);
    bf16x8 Blo0 = ld_frag16(bB + rd_lo0), Blo1 = ld_frag16(bB + rd_lo1);

    // ---- group A MFMAs (x first, then split-bf16 h terms) ----
    f32x4 aRA  = MFMA(axw[0], xfA, bR4);
    f32x4 aZA  = MFMA(axw[1], xfA, bZ4);
    f32x4 aNxA = MFMA(axw[2], xfA, bNx4);
    aRA = MFMA(whi[0][0], Ahi0, aRA); aRA = MFMA(whi[0][1], Ahi1, aRA);
    aRA = MFMA(whi[0][0], Alo0, aRA); aRA = MFMA(whi[0][1], Alo1, aRA);
    aRA = MFMA(wlo[0][0], Ahi0, aRA); aRA = MFMA(wlo[0][1], Ahi1, aRA);
    aZA = MFMA(whi[1][0], Ahi0, aZA); aZA = MFMA(whi[1][1], Ahi1, aZA);
    aZA = MFMA(whi[1][0], Alo0, aZA); aZA = MFMA(whi[1][1], Alo1, aZA);
    aZA = MFMA(wlo[1][0], Ahi0, aZA); aZA = MFMA(wlo[1][1], Ahi1, aZA);
    f32x4 aNhA = MFMA(whi[2][0], Ahi0, bNh4);
    aNhA = MFMA(whi[2][1], Ahi1, aNhA);
    aNhA = MFMA(whi[2][0], Alo0, aNhA); aNhA = MFMA(whi[2][1], Alo1, aNhA);
    aNhA = MFMA(wlo[2][0], Ahi0, aNhA); aNhA = MFMA(wlo[2][1], Ahi1, aNhA);

    // ---- group B MFMAs ----
    f32x4 aRB  = MFMA(axw[0], xfB, bR4);
    f32x4 aZB  = MFMA(axw[1], xfB, bZ4);
    f32x4 aNxB = MFMA(axw[2], xfB, bNx4);
    aRB = MFMA(whi[0][0], Bhi0, aRB); aRB = MFMA(whi[0][1], Bhi1, aRB);
    aRB = MFMA(whi[0][0], Blo0, aRB); aRB = MFMA(whi[0][1], Blo1, aRB);
    aRB = MFMA(wlo[0][0], Bhi0, aRB); aRB = MFMA(wlo[0][1], Bhi1, aRB);
    aZB = MFMA(whi[1][0], Bhi0, aZB); aZB = MFMA(whi[1][1], Bhi1, aZB);
    aZB = MFMA(whi[1][0], Blo0, aZB); aZB = MFMA(whi[1][1], Blo1, aZB);
    aZB = MFMA(wlo[1][0], Bhi0, aZB); aZB = MFMA(wlo[1][1], Bhi1, aZB);
    f32x4 aNhB = MFMA(whi[2][0], Bhi0, bNh4);
    aNhB = MFMA(whi[2][1], Bhi1, aNhB);
    aNhB = MFMA(whi[2][0], Blo0, aNhB); aNhB = MFMA(whi[2][1], Blo1, aNhB);
    aNhB = MFMA(wlo[2][0], Bhi0, aNhB); aNhB = MFMA(wlo[2][1], Bhi1, aNhB);

    // pack next x fragments (independent; hides under MFMA drain)
    bf16x8 xfA_n = pack_xfrag(xnaA, xnbA, hi_grp);
    bf16x8 xfB_n = pack_xfrag(xnaB, xnbB, hi_grp);

    // ---- gates: A runs while B's MFMA chain drains, then B ----
    gates4(aRA, aZA, aNhA, aNxA, hregA, sH[0], wr_hi, wr_lo);
    gates4(aRB, aZB, aNhB, aNxB, hregB, sH[1], wr_hi, wr_lo);

    __syncthreads();   // h(t+1) visible to all waves
    xfA = xfA_n; xfB = xfB_n;
  }

  // ---- head: out[b] = sum_hidden h[hid][b]*fc_w[hid] + fc_b ----
  float sA, sB;
  {
    const int hx = wv * 16 + grp * 4;
    f32x4 fw = {fc_w[hx], fc_w[hx + 1], fc_w[hx + 2], fc_w[hx + 3]};
    sA = hregA[0] * fw[0] + hregA[1] * fw[1] + hregA[2] * fw[2] + hregA[3] * fw[3];
    sB = hregB[0] * fw[0] + hregB[1] * fw[1] + hregB[2] * fw[2] + hregB[3] * fw[3];
  }
  sA += __shfl_xor(sA, 16, 64); sA += __shfl_xor(sA, 32, 64);
  sB += __shfl_xor(sB, 16, 64); sB += __shfl_xor(sB, 32, 64);
  if (lane < 16) {
    s_red[0][wv][lane] = sA;
    s_red[1][wv][lane] = sB;
  }
  __syncthreads();
  if (tid < 32) {
    const int g = tid >> 4, c = tid & 15;
    out[rb + tid] = s_red[g][0][c] + s_red[g][1][c] + s_red[g][2][c]
                  + s_red[g][3][c] + fc_b[0];
  }
}

extern "C" void kernel_launch(void* const* d_in, const int* in_sizes, int n_in,
                              void* d_out, int out_size, void* d_ws, size_t ws_size,
                              hipStream_t stream) {
  (void)in_sizes; (void)n_in; (void)d_ws; (void)ws_size;
  const float* x    = (const float*)d_in[0];
  const float* w_ih = (const float*)d_in[1];
  const float* w_hh = (const float*)d_in[2];
  const float* b_ih = (const float*)d_in[3];
  const float* b_hh = (const float*)d_in[4];
  const float* fc_w = (const float*)d_in[5];
  const float* fc_b = (const float*)d_in[6];
  float* out = (float*)d_out;
  const int nblocks = out_size / RB;  // 4096/32 = 128 blocks
  gru_fused<<<dim3(nblocks), dim3(256), 0, stream>>>(x, w_ih, w_hh, b_ih, b_hh,
                                                     fc_w, fc_b, out);
}

// Round 8
// 179.275 us; speedup vs baseline: 1.1458x; 1.1458x over previous
//
#include <hip/hip_runtime.h>
#include <stdint.h>

// GRU: B=4096, T=128, I=16, H=64. Gate order r,z,n (PyTorch).
// v7 = v5 geometry (RB=16, 256 blocks = 1/CU, 4 waves, swapped-operand GEMM
// gates[3H x 16b] = W @ h, 21 MFMAs/wave/step) with three stall cuts:
//  1. h LDS back to v2's measured-zero-conflict layout (128B rows, 16B-chunk
//     XOR swizzle), double-buffered (fixes v5's 15.7M conflicts + latent race).
//  2. Per-gate MFMA chains split 7-deep -> two parallel chains (4+3) + one
//     f32x4 add; 7 chains round-robin interleaved (no dependent back-to-back).
//  3. exp2(aR)/exp2(aZ) issued right after their joins to overlap trans with
//     the N-gate MFMA issue.
// Split-bf16 (hi*hi + hi*lo + lo*hi) recurrence; exp2 scales pre-folded into
// weights; biases in MFMA C-init. 1 barrier/step.

#define T_STEPS 128
#define NI 16
#define NH 64
#define RB 16

typedef float    f32x4  __attribute__((ext_vector_type(4)));
typedef uint32_t u32x4  __attribute__((ext_vector_type(4)));
typedef uint32_t u32x2  __attribute__((ext_vector_type(2)));
typedef short    bf16x8 __attribute__((ext_vector_type(8)));  // MFMA operand
typedef __bf16   bfv8   __attribute__((ext_vector_type(8)));

static constexpr float LOG2E = 1.4426950408889634f;

static __device__ __forceinline__ uint32_t fbits(float f) { return __builtin_bit_cast(uint32_t, f); }
static __device__ __forceinline__ float    bitsf(uint32_t u) { return __builtin_bit_cast(float, u); }

static __device__ __forceinline__ bf16x8 ld_frag16(const unsigned char* p) {
  u32x4 v = *(const u32x4*)p;                           // ds_read_b128
  return __builtin_bit_cast(bf16x8, v);
}

#define MFMA(A, B, C) __builtin_amdgcn_mfma_f32_16x16x32_bf16(A, B, C, 0, 0, 0)

// pack split-bf16 x fragment (proven v5 pattern)
static __device__ __forceinline__ bf16x8 pack_xfrag(f32x4 xa, f32x4 xb, bool hi_grp) {
  float v[8];
  #pragma unroll
  for (int j = 0; j < 4; ++j) {
    float x0 = xa[j], x1 = xb[j];
    float b0 = bitsf(fbits(x0) & 0xffff0000u);
    float b1 = bitsf(fbits(x1) & 0xffff0000u);
    v[j]     = hi_grp ? x0 : (x0 - b0);
    v[4 + j] = hi_grp ? x1 : (x1 - b1);
  }
  uint32_t d0 = __builtin_amdgcn_perm(fbits(v[1]), fbits(v[0]), 0x07060302u);
  uint32_t d1 = __builtin_amdgcn_perm(fbits(v[3]), fbits(v[2]), 0x07060302u);
  uint32_t d2 = __builtin_amdgcn_perm(fbits(v[5]), fbits(v[4]), 0x07060302u);
  uint32_t d3 = __builtin_amdgcn_perm(fbits(v[7]), fbits(v[6]), 0x07060302u);
  u32x4 u = {d0, d1, d2, d3};
  return __builtin_bit_cast(bf16x8, u);
}

__global__ __launch_bounds__(256)
void gru_fused(const float* __restrict__ x,
               const float* __restrict__ w_ih,
               const float* __restrict__ w_hh,
               const float* __restrict__ b_ih,
               const float* __restrict__ b_hh,
               const float* __restrict__ fc_w,
               const float* __restrict__ fc_b,
               float* __restrict__ out)
{
  // [buf][plane hi/lo][16 batch rows x 64 hidden, 128B/row, chunk-swizzled]
  __shared__ __align__(16) unsigned char sH[2][2][2048];
  __shared__ float s_red[4][16];

  const int tid  = threadIdx.x;
  const int lane = tid & 63;
  const int wv   = tid >> 6;       // wave 0..3: hidden [16wv,16wv+16)
  const int colg = lane & 15;      // batch column (B-frag n / C col)
  const int grp  = lane >> 4;      // k-group / C row-group
  const int rb   = blockIdx.x * RB;
  const int hc   = wv * 16 + colg; // W A-frag row index

  // zero both buffers (8192 B = 2048 dwords)
  {
    uint32_t* p = (uint32_t*)sH;
    #pragma unroll
    for (int i = 0; i < 8; ++i) p[tid + 256 * i] = 0u;
  }

  // ---- W A-frags (registers, once), scales pre-folded ----
  // A-frag: lane (grp,colg) holds A[m=colg][k=kt*32+grp*8+j]
  const float scl0 = -LOG2E, scl2 = 2.0f * LOG2E;
  bf16x8 whi[3][2], wlo[3][2], axw[3];
  #pragma unroll
  for (int g = 0; g < 3; ++g) {
    const float s = (g == 2) ? scl2 : scl0;
    const float* wr = w_hh + (size_t)(g * 64 + hc) * NH + grp * 8;
    #pragma unroll
    for (int kt = 0; kt < 2; ++kt) {
      bfv8 vhi, vlo;
      #pragma unroll
      for (int j = 0; j < 8; ++j) {
        float w = wr[kt * 32 + j] * s;
        __bf16 hi = (__bf16)w;                 // RNE
        vhi[j] = hi;
        vlo[j] = (__bf16)(w - (float)hi);
      }
      whi[g][kt] = __builtin_bit_cast(bf16x8, vhi);
      wlo[g][kt] = __builtin_bit_cast(bf16x8, vlo);
    }
    const float* wi = w_ih + (size_t)(g * 64 + hc) * NI + (grp & 1) * 8;
    bfv8 vx;
    #pragma unroll
    for (int j = 0; j < 8; ++j) vx[j] = (__bf16)(wi[j] * s);
    axw[g] = __builtin_bit_cast(bf16x8, vx);
  }

  // per-reg biases (C-init); reg q -> hidden wv*16 + grp*4 + q
  f32x4 bR4, bZ4, bNh4, bNx4;
  #pragma unroll
  for (int q = 0; q < 4; ++q) {
    const int hx = wv * 16 + grp * 4 + q;
    bR4[q]  = scl0 * (b_ih[hx] + b_hh[hx]);
    bZ4[q]  = scl0 * (b_ih[64 + hx] + b_hh[64 + hx]);
    bNh4[q] = scl2 * b_hh[128 + hx];
    bNx4[q] = scl2 * b_ih[128 + hx];
  }

  // ---- LDS addressing (t-invariant), v2's zero-conflict pattern ----
  // h_addr(row=batch colg, col=hidden) = colg*128 + ((col>>3 ^ swz)<<4) + (col&7)*2
  const int swz = colg & 7;
  const int rd0 = colg * 128 + ((0 + grp) ^ swz) * 16;   // kt=0 chunk grp
  const int rd1 = colg * 128 + ((4 + grp) ^ swz) * 16;   // kt=1 chunk 4+grp
  // write: lane's 4 cells = hidden wv*16+grp*4+{0..3} at batch colg -> 8B run
  const int wrh = colg * 128 + ((wv * 2 + (grp >> 1)) ^ swz) * 16 + (grp & 1) * 8;

  float hreg[4] = {0.f, 0.f, 0.f, 0.f};  // h[hidden wv*16+grp*4+q][batch colg]

  const float* xp = x + (size_t)(rb + colg) * T_STEPS * NI + (grp & 1) * 8;
  const bool hi_grp = (grp < 2);
  bf16x8 xf = pack_xfrag(*(const f32x4*)xp, *(const f32x4*)(xp + 4), hi_grp);

  const f32x4 zz = {0.f, 0.f, 0.f, 0.f};

  __syncthreads();

  for (int t = 0; t < T_STEPS; ++t) {
    // h B-frags from buffer t&1 (issue LDS reads first)
    const unsigned char* rb_hi = &sH[t & 1][0][0];
    const unsigned char* rb_lo = &sH[t & 1][1][0];
    bf16x8 hi0 = ld_frag16(rb_hi + rd0);
    bf16x8 hi1 = ld_frag16(rb_hi + rd1);
    bf16x8 lo0 = ld_frag16(rb_lo + rd0);
    bf16x8 lo1 = ld_frag16(rb_lo + rd1);

    // prefetch next step's x
    const int tn = (t < T_STEPS - 1) ? (t + 1) : t;
    f32x4 xna = *(const f32x4*)(xp + (size_t)tn * NI);
    f32x4 xnb = *(const f32x4*)(xp + (size_t)tn * NI + 4);

    // ---- 7 parallel MFMA chains, round-robin issue (max depth 4) ----
    f32x4 cR1 = MFMA(axw[0], xf, bR4);
    f32x4 cZ1 = MFMA(axw[1], xf, bZ4);
    f32x4 aNx = MFMA(axw[2], xf, bNx4);
    f32x4 cR2 = MFMA(whi[0][1], lo1, zz);
    f32x4 cZ2 = MFMA(whi[1][1], lo1, zz);
    f32x4 cN2 = MFMA(whi[2][1], lo1, zz);
    f32x4 cN1 = MFMA(whi[2][0], hi0, bNh4);
    cR1 = MFMA(whi[0][0], hi0, cR1); cZ1 = MFMA(whi[1][0], hi0, cZ1);
    cR2 = MFMA(wlo[0][0], hi0, cR2); cZ2 = MFMA(wlo[1][0], hi0, cZ2);
    cN2 = MFMA(wlo[2][0], hi0, cN2);
    cN1 = MFMA(whi[2][1], hi1, cN1);
    cR1 = MFMA(whi[0][1], hi1, cR1); cZ1 = MFMA(whi[1][1], hi1, cZ1);
    cR2 = MFMA(wlo[0][1], hi1, cR2); cZ2 = MFMA(wlo[1][1], hi1, cZ2);
    cN2 = MFMA(wlo[2][1], hi1, cN2);
    cN1 = MFMA(whi[2][0], lo0, cN1);
    cR1 = MFMA(whi[0][0], lo0, cR1); cZ1 = MFMA(whi[1][0], lo0, cZ1);

    f32x4 aR = cR1 + cR2;
    f32x4 aZ = cZ1 + cZ2;

    // early trans issue: overlaps with N-chain MFMA drain
    float eR0 = __builtin_amdgcn_exp2f(aR[0]), eR1 = __builtin_amdgcn_exp2f(aR[1]);
    float eR2 = __builtin_amdgcn_exp2f(aR[2]), eR3 = __builtin_amdgcn_exp2f(aR[3]);
    float eZ0 = __builtin_amdgcn_exp2f(aZ[0]), eZ1 = __builtin_amdgcn_exp2f(aZ[1]);
    float eZ2 = __builtin_amdgcn_exp2f(aZ[2]), eZ3 = __builtin_amdgcn_exp2f(aZ[3]);

    f32x4 aNh = cN1 + cN2;

    // pack next x fragment (independent; fills issue slots)
    bf16x8 xf_n = pack_xfrag(xna, xnb, hi_grp);

    // ---- gates + h update (lane-local, 4 cells) ----
    float eRq[4] = {eR0, eR1, eR2, eR3};
    float eZq[4] = {eZ0, eZ1, eZ2, eZ3};
    float h[4];
    #pragma unroll
    for (int q = 0; q < 4; ++q) {
      float r = __builtin_amdgcn_rcpf(1.0f + eRq[q]);
      float z = __builtin_amdgcn_rcpf(1.0f + eZq[q]);
      float n = fmaf(-2.0f, __builtin_amdgcn_rcpf(
                    __builtin_amdgcn_exp2f(fmaf(r, aNh[q], aNx[q])) + 1.0f), 1.0f);
      h[q] = n + z * (hreg[q] - n);
      hreg[q] = h[q];
    }

    // pack hi (trunc) + lo (residual), write to buffer (t+1)&1: 2x ds_write_b64
    {
      unsigned char* wb_hi = &sH[(t + 1) & 1][0][0];
      unsigned char* wb_lo = &sH[(t + 1) & 1][1][0];
      uint32_t hi01 = __builtin_amdgcn_perm(fbits(h[1]), fbits(h[0]), 0x07060302u);
      uint32_t hi23 = __builtin_amdgcn_perm(fbits(h[3]), fbits(h[2]), 0x07060302u);
      float l0 = h[0] - bitsf(fbits(h[0]) & 0xffff0000u);
      float l1 = h[1] - bitsf(fbits(h[1]) & 0xffff0000u);
      float l2 = h[2] - bitsf(fbits(h[2]) & 0xffff0000u);
      float l3 = h[3] - bitsf(fbits(h[3]) & 0xffff0000u);
      uint32_t lo01 = __builtin_amdgcn_perm(fbits(l1), fbits(l0), 0x07060302u);
      uint32_t lo23 = __builtin_amdgcn_perm(fbits(l3), fbits(l2), 0x07060302u);
      u32x2 whiv = {hi01, hi23};
      u32x2 wlov = {lo01, lo23};
      *(u32x2*)(wb_hi + wrh) = whiv;
      *(u32x2*)(wb_lo + wrh) = wlov;
    }
    __syncthreads();   // h(t+1) buffer complete
    xf = xf_n;
  }

  // ---- head: out[b=rb+colg] = sum_hidden h[hid][b]*fc_w[hid] + fc_b ----
  float s;
  {
    const int hx = wv * 16 + grp * 4;
    s = hreg[0] * fc_w[hx] + hreg[1] * fc_w[hx + 1]
      + hreg[2] * fc_w[hx + 2] + hreg[3] * fc_w[hx + 3];
  }
  s += __shfl_xor(s, 16, 64);
  s += __shfl_xor(s, 32, 64);       // sum over the 4 k-groups at fixed colg
  if (lane < 16) s_red[wv][lane] = s;
  __syncthreads();
  if (tid < 16) {
    out[rb + tid] = s_red[0][tid] + s_red[1][tid] + s_red[2][tid] + s_red[3][tid]
                  + fc_b[0];
  }
}

extern "C" void kernel_launch(void* const* d_in, const int* in_sizes, int n_in,
                              void* d_out, int out_size, void* d_ws, size_t ws_size,
                              hipStream_t stream) {
  (void)in_sizes; (void)n_in; (void)d_ws; (void)ws_size;
  const float* x    = (const float*)d_in[0];
  const float* w_ih = (const float*)d_in[1];
  const float* w_hh = (const float*)d_in[2];
  const float* b_ih = (const float*)d_in[3];
  const float* b_hh = (const float*)d_in[4];
  const float* fc_w = (const float*)d_in[5];
  const float* fc_b = (const float*)d_in[6];
  float* out = (float*)d_out;
  const int nblocks = out_size / RB;  // 4096/16 = 256 blocks, 1 per CU
  gru_fused<<<dim3(nblocks), dim3(256), 0, stream>>>(x, w_ih, w_hh, b_ih, b_hh,
                                                     fc_w, fc_b, out);
}

// Round 10
// 148.608 us; speedup vs baseline: 1.3823x; 1.2064x over previous
//
#include <hip/hip_runtime.h>
#include <stdint.h>

// GRU: B=4096, T=128, I=16, H=64. Gate order r,z,n (PyTorch).
// v8 = v5 geometry+body (RB=16, 256 blocks = 1/CU, 4 waves, swapped-operand
// GEMM gates[3Hx16b] = W @ h, sequential MFMA chains — v7's hand-interleave
// regressed, reverted) + v7's zero-conflict double-buffered h LDS
// + NO-DRAIN BARRIER: in-loop __syncthreads() replaced by
//   s_waitcnt lgkmcnt(0); s_barrier   (inline asm + builtin)
// so the per-step x prefetch (register-destined, no cross-wave semantics)
// is NOT drained at the barrier (m97: __syncthreads emits vmcnt(0) drain =
// the dominant stall). x prefetched 2 steps deep so its counted-vmcnt wait
// at pack time is fully covered (~1.5 steps >> 900cyc HBM latency).
// Split-bf16 (hi*hi + hi*lo + lo*hi) recurrence; exp2 scales pre-folded;
// biases in MFMA C-init. 1 barrier/step.

#define T_STEPS 128
#define NI 16
#define NH 64
#define RB 16

typedef float    f32x4  __attribute__((ext_vector_type(4)));
typedef uint32_t u32x4  __attribute__((ext_vector_type(4)));
typedef uint32_t u32x2  __attribute__((ext_vector_type(2)));
typedef short    bf16x8 __attribute__((ext_vector_type(8)));  // MFMA operand
typedef __bf16   bfv8   __attribute__((ext_vector_type(8)));

static constexpr float LOG2E = 1.4426950408889634f;

static __device__ __forceinline__ uint32_t fbits(float f) { return __builtin_bit_cast(uint32_t, f); }
static __device__ __forceinline__ float    bitsf(uint32_t u) { return __builtin_bit_cast(float, u); }

static __device__ __forceinline__ bf16x8 ld_frag16(const unsigned char* p) {
  u32x4 v = *(const u32x4*)p;                           // ds_read_b128
  return __builtin_bit_cast(bf16x8, v);
}

#define MFMA(A, B, C) __builtin_amdgcn_mfma_f32_16x16x32_bf16(A, B, C, 0, 0, 0)

// pack split-bf16 x fragment (proven v5 pattern)
static __device__ __forceinline__ bf16x8 pack_xfrag(f32x4 xa, f32x4 xb, bool hi_grp) {
  float v[8];
  #pragma unroll
  for (int j = 0; j < 4; ++j) {
    float x0 = xa[j], x1 = xb[j];
    float b0 = bitsf(fbits(x0) & 0xffff0000u);
    float b1 = bitsf(fbits(x1) & 0xffff0000u);
    v[j]     = hi_grp ? x0 : (x0 - b0);
    v[4 + j] = hi_grp ? x1 : (x1 - b1);
  }
  uint32_t d0 = __builtin_amdgcn_perm(fbits(v[1]), fbits(v[0]), 0x07060302u);
  uint32_t d1 = __builtin_amdgcn_perm(fbits(v[3]), fbits(v[2]), 0x07060302u);
  uint32_t d2 = __builtin_amdgcn_perm(fbits(v[5]), fbits(v[4]), 0x07060302u);
  uint32_t d3 = __builtin_amdgcn_perm(fbits(v[7]), fbits(v[6]), 0x07060302u);
  u32x4 u = {d0, d1, d2, d3};
  return __builtin_bit_cast(bf16x8, u);
}

__global__ __launch_bounds__(256)
void gru_fused(const float* __restrict__ x,
               const float* __restrict__ w_ih,
               const float* __restrict__ w_hh,
               const float* __restrict__ b_ih,
               const float* __restrict__ b_hh,
               const float* __restrict__ fc_w,
               const float* __restrict__ fc_b,
               float* __restrict__ out)
{
  // [buf][plane hi/lo][16 batch rows x 64 hidden, 128B/row, chunk-swizzled]
  __shared__ __align__(16) unsigned char sH[2][2][2048];
  __shared__ float s_red[4][16];

  const int tid  = threadIdx.x;
  const int lane = tid & 63;
  const int wv   = tid >> 6;       // wave 0..3: hidden [16wv,16wv+16)
  const int colg = lane & 15;      // batch column (B-frag n / C col)
  const int grp  = lane >> 4;      // k-group / C row-group
  const int rb   = blockIdx.x * RB;
  const int hc   = wv * 16 + colg; // W A-frag row index

  // zero both buffers (8192 B = 2048 dwords)
  {
    uint32_t* p = (uint32_t*)sH;
    #pragma unroll
    for (int i = 0; i < 8; ++i) p[tid + 256 * i] = 0u;
  }

  // ---- W A-frags (registers, once), scales pre-folded ----
  // A-frag: lane (grp,colg) holds A[m=colg][k=kt*32+grp*8+j]
  const float scl0 = -LOG2E, scl2 = 2.0f * LOG2E;
  bf16x8 whi[3][2], wlo[3][2], axw[3];
  #pragma unroll
  for (int g = 0; g < 3; ++g) {
    const float s = (g == 2) ? scl2 : scl0;
    const float* wr = w_hh + (size_t)(g * 64 + hc) * NH + grp * 8;
    #pragma unroll
    for (int kt = 0; kt < 2; ++kt) {
      bfv8 vhi, vlo;
      #pragma unroll
      for (int j = 0; j < 8; ++j) {
        float w = wr[kt * 32 + j] * s;
        __bf16 hi = (__bf16)w;                 // RNE
        vhi[j] = hi;
        vlo[j] = (__bf16)(w - (float)hi);
      }
      whi[g][kt] = __builtin_bit_cast(bf16x8, vhi);
      wlo[g][kt] = __builtin_bit_cast(bf16x8, vlo);
    }
    const float* wi = w_ih + (size_t)(g * 64 + hc) * NI + (grp & 1) * 8;
    bfv8 vx;
    #pragma unroll
    for (int j = 0; j < 8; ++j) vx[j] = (__bf16)(wi[j] * s);
    axw[g] = __builtin_bit_cast(bf16x8, vx);
  }

  // per-reg biases (C-init); reg q -> hidden wv*16 + grp*4 + q
  f32x4 bR4, bZ4, bNh4, bNx4;
  #pragma unroll
  for (int q = 0; q < 4; ++q) {
    const int hx = wv * 16 + grp * 4 + q;
    bR4[q]  = scl0 * (b_ih[hx] + b_hh[hx]);
    bZ4[q]  = scl0 * (b_ih[64 + hx] + b_hh[64 + hx]);
    bNh4[q] = scl2 * b_hh[128 + hx];
    bNx4[q] = scl2 * b_ih[128 + hx];
  }

  // ---- LDS addressing (t-invariant), zero-conflict chunk-XOR layout ----
  const int swz = colg & 7;
  const int rd0 = colg * 128 + ((0 + grp) ^ swz) * 16;   // kt=0 chunk grp
  const int rd1 = colg * 128 + ((4 + grp) ^ swz) * 16;   // kt=1 chunk 4+grp
  // write: lane's 4 cells = hidden wv*16+grp*4+{0..3} at batch colg -> 8B run
  const int wrh = colg * 128 + ((wv * 2 + (grp >> 1)) ^ swz) * 16 + (grp & 1) * 8;

  float hreg[4] = {0.f, 0.f, 0.f, 0.f};  // h[hidden wv*16+grp*4+q][batch colg]

  const float* xp = x + (size_t)(rb + colg) * T_STEPS * NI + (grp & 1) * 8;
  const bool hi_grp = (grp < 2);

  // ---- 2-deep x pipeline: xf = frag(t), (x1a,x1b) = raw x(t+1) in flight
  bf16x8 xf = pack_xfrag(*(const f32x4*)xp, *(const f32x4*)(xp + 4), hi_grp);
  f32x4 x1a = *(const f32x4*)(xp + NI);
  f32x4 x1b = *(const f32x4*)(xp + NI + 4);

  __syncthreads();

  for (int t = 0; t < T_STEPS; ++t) {
    // issue x(t+2) load (stays in flight across the no-drain barrier)
    const int tn2 = (t < T_STEPS - 2) ? (t + 2) : (T_STEPS - 1);
    f32x4 x2a = *(const f32x4*)(xp + (size_t)tn2 * NI);
    f32x4 x2b = *(const f32x4*)(xp + (size_t)tn2 * NI + 4);

    // h B-frags from buffer t&1 (issue LDS reads first)
    const unsigned char* rb_hi = &sH[t & 1][0][0];
    const unsigned char* rb_lo = &sH[t & 1][1][0];
    bf16x8 hi0 = ld_frag16(rb_hi + rd0);
    bf16x8 hi1 = ld_frag16(rb_hi + rd1);
    bf16x8 lo0 = ld_frag16(rb_lo + rd0);
    bf16x8 lo1 = ld_frag16(rb_lo + rd1);

    // ---- v5 sequential chains: x-MFMAs first (register-only), then h ----
    f32x4 aR  = MFMA(axw[0], xf, bR4);
    f32x4 aZ  = MFMA(axw[1], xf, bZ4);
    f32x4 aNx = MFMA(axw[2], xf, bNx4);

    aR = MFMA(whi[0][0], hi0, aR); aR = MFMA(whi[0][1], hi1, aR);
    aR = MFMA(whi[0][0], lo0, aR); aR = MFMA(whi[0][1], lo1, aR);
    aR = MFMA(wlo[0][0], hi0, aR); aR = MFMA(wlo[0][1], hi1, aR);

    aZ = MFMA(whi[1][0], hi0, aZ); aZ = MFMA(whi[1][1], hi1, aZ);
    aZ = MFMA(whi[1][0], lo0, aZ); aZ = MFMA(whi[1][1], lo1, aZ);
    aZ = MFMA(wlo[1][0], hi0, aZ); aZ = MFMA(wlo[1][1], hi1, aZ);

    f32x4 aNh = MFMA(whi[2][0], hi0, bNh4);
    aNh = MFMA(whi[2][1], hi1, aNh);
    aNh = MFMA(whi[2][0], lo0, aNh); aNh = MFMA(whi[2][1], lo1, aNh);
    aNh = MFMA(wlo[2][0], hi0, aNh); aNh = MFMA(wlo[2][1], hi1, aNh);

    // ---- gates + h update (lane-local, 4 cells) ----
    float h[4];
    #pragma unroll
    for (int q = 0; q < 4; ++q) {
      float r = __builtin_amdgcn_rcpf(1.0f + __builtin_amdgcn_exp2f(aR[q]));
      float z = __builtin_amdgcn_rcpf(1.0f + __builtin_amdgcn_exp2f(aZ[q]));
      float n = fmaf(-2.0f, __builtin_amdgcn_rcpf(
                    __builtin_amdgcn_exp2f(fmaf(r, aNh[q], aNx[q])) + 1.0f), 1.0f);
      h[q] = n + z * (hreg[q] - n);
      hreg[q] = h[q];
    }

    // pack hi (trunc) + lo (residual), write to buffer (t+1)&1: 2x ds_write_b64
    {
      unsigned char* wb_hi = &sH[(t + 1) & 1][0][0];
      unsigned char* wb_lo = &sH[(t + 1) & 1][1][0];
      uint32_t hi01 = __builtin_amdgcn_perm(fbits(h[1]), fbits(h[0]), 0x07060302u);
      uint32_t hi23 = __builtin_amdgcn_perm(fbits(h[3]), fbits(h[2]), 0x07060302u);
      float l0 = h[0] - bitsf(fbits(h[0]) & 0xffff0000u);
      float l1 = h[1] - bitsf(fbits(h[1]) & 0xffff0000u);
      float l2 = h[2] - bitsf(fbits(h[2]) & 0xffff0000u);
      float l3 = h[3] - bitsf(fbits(h[3]) & 0xffff0000u);
      uint32_t lo01 = __builtin_amdgcn_perm(fbits(l1), fbits(l0), 0x07060302u);
      uint32_t lo23 = __builtin_amdgcn_perm(fbits(l3), fbits(l2), 0x07060302u);
      u32x2 whiv = {hi01, hi23};
      u32x2 wlov = {lo01, lo23};
      *(u32x2*)(wb_hi + wrh) = whiv;
      *(u32x2*)(wb_lo + wrh) = wlov;
    }

    // pack x(t+1) frag (VALU, overlaps ds_write retire; x1 loaded 1.5 steps
    // ago -> counted-vmcnt wait is a no-op)
    xf = pack_xfrag(x1a, x1b, hi_grp);

    // NO-DRAIN BARRIER: drain LDS ops only; x loads stay in flight.
    asm volatile("s_waitcnt lgkmcnt(0)" ::: "memory");
    __builtin_amdgcn_s_barrier();

    x1a = x2a; x1b = x2b;
  }

  // ---- head: out[b=rb+colg] = sum_hidden h[hid][b]*fc_w[hid] + fc_b ----
  float s;
  {
    const int hx = wv * 16 + grp * 4;
    s = hreg[0] * fc_w[hx] + hreg[1] * fc_w[hx + 1]
      + hreg[2] * fc_w[hx + 2] + hreg[3] * fc_w[hx + 3];
  }
  s += __shfl_xor(s, 16, 64);
  s += __shfl_xor(s, 32, 64);       // sum over the 4 k-groups at fixed colg
  if (lane < 16) s_red[wv][lane] = s;
  __syncthreads();
  if (tid < 16) {
    out[rb + tid] = s_red[0][tid] + s_red[1][tid] + s_red[2][tid] + s_red[3][tid]
                  + fc_b[0];
  }
}

extern "C" void kernel_launch(void* const* d_in, const int* in_sizes, int n_in,
                              void* d_out, int out_size, void* d_ws, size_t ws_size,
                              hipStream_t stream) {
  (void)in_sizes; (void)n_in; (void)d_ws; (void)ws_size;
  const float* x    = (const float*)d_in[0];
  const float* w_ih = (const float*)d_in[1];
  const float* w_hh = (const float*)d_in[2];
  const float* b_ih = (const float*)d_in[3];
  const float* b_hh = (const float*)d_in[4];
  const float* fc_w = (const float*)d_in[5];
  const float* fc_b = (const float*)d_in[6];
  float* out = (float*)d_out;
  const int nblocks = out_size / RB;  // 4096/16 = 256 blocks, 1 per CU
  gru_fused<<<dim3(nblocks), dim3(256), 0, stream>>>(x, w_ih, w_hh, b_ih, b_hh,
                                                     fc_w, fc_b, out);
}